// Round 1
// baseline (21216.800 us; speedup 1.0000x reference)
//
#include <hip/hip_runtime.h>
#include <hip/hip_bf16.h>
#include <stdint.h>

// Problem sizes (fixed)
#define NB 512     // batch
#define NS 256     // source length
#define ND 256     // hidden dim
#define NT 256     // decode steps
#define NO 3       // output dim
#define G3 768     // 3*ND
#define KIH 259    // ND+NO

#define LOG2E 1.44269504088896340736f

#if __has_builtin(__builtin_amdgcn_exp2f)
__device__ __forceinline__ float exp2_fast(float x){ return __builtin_amdgcn_exp2f(x); }
#else
__device__ __forceinline__ float exp2_fast(float x){ return exp2f(x); }
#endif
#if __has_builtin(__builtin_amdgcn_rcpf)
__device__ __forceinline__ float rcp_fast(float x){ return __builtin_amdgcn_rcpf(x); }
#else
__device__ __forceinline__ float rcp_fast(float x){ return 1.0f/x; }
#endif

__device__ __forceinline__ float tanh_f(float x){
  // tanh(x) = 1 - 2/(exp(2x)+1); exp(2x)=2^(2*log2e*x). 2 transcendental ops.
  float e = exp2_fast(x * (2.0f*LOG2E));
  return 1.0f - 2.0f*rcp_fast(e + 1.0f);
}
__device__ __forceinline__ float sigm_f(float x){
  return rcp_fast(1.0f + exp2_fast(-x*LOG2E));
}
__device__ __forceinline__ float bflo(uint32_t u){ return __uint_as_float(u<<16); }
__device__ __forceinline__ float bfhi(uint32_t u){ return __uint_as_float(u & 0xffff0000u); }
__device__ __forceinline__ uint16_t f2bf(float f){   // round-to-nearest-even bf16
  uint32_t u = __float_as_uint(f);
  return (uint16_t)((u + 0x7fffu + ((u>>16)&1u)) >> 16);
}

// ---------------- prep kernels ----------------

// dst[c*R + r] = src[r*C + c]  (dst is C x R)
__global__ void k_transpose(const float* __restrict__ src, float* __restrict__ dst,
                            int R, int C){
  int idx = blockIdx.x*256 + threadIdx.x;
  if (idx < R*C){
    int r = idx / C, c = idx - r*C;
    dst[c*R + r] = src[idx];
  }
}

__global__ void k_cvt(const float* __restrict__ src, uint16_t* __restrict__ dst, int n4){
  int i = blockIdx.x*256 + threadIdx.x;
  if (i < n4){
    float4 v = ((const float4*)src)[i];
    ushort4 o;
    o.x=f2bf(v.x); o.y=f2bf(v.y); o.z=f2bf(v.z); o.w=f2bf(v.w);
    ((ushort4*)dst)[i] = o;
  }
}

// UK[b][e4][s][4] (bf16, d-interleaved-by-4) = e_all[b,s,:] . Ua[e,:] + bu[e]
// block: 16 rows (m = b*NS+s) x 256 cols (e), 256 threads (thread = e)
__global__ void __launch_bounds__(256) k_uk(const float* __restrict__ e_all,
    const float* __restrict__ UaT, const float* __restrict__ bu,
    uint16_t* __restrict__ UK){
  __shared__ float At[ND][20];   // A transposed [d][row], pad 20 (16B-aligned rows, conflict-lite)
  const int t = threadIdx.x;
  const int m0 = blockIdx.x * 16;
  const int b  = m0 >> 8;
  const int s0 = m0 & (NS-1);
  #pragma unroll
  for (int i=0;i<16;i++)
    At[t][i] = e_all[(size_t)(m0+i)*ND + t];
  __syncthreads();
  float acc[16];
  float bue = bu[t];
  #pragma unroll
  for (int i=0;i<16;i++) acc[i] = bue;
  for (int d=0; d<ND; ++d){
    float u = UaT[d*ND + t];                 // coalesced, L2-resident
    const float4 a0 = *(const float4*)&At[d][0];
    const float4 a1 = *(const float4*)&At[d][4];
    const float4 a2 = *(const float4*)&At[d][8];
    const float4 a3 = *(const float4*)&At[d][12];
    acc[0]+=a0.x*u;  acc[1]+=a0.y*u;  acc[2]+=a0.z*u;  acc[3]+=a0.w*u;
    acc[4]+=a1.x*u;  acc[5]+=a1.y*u;  acc[6]+=a1.z*u;  acc[7]+=a1.w*u;
    acc[8]+=a2.x*u;  acc[9]+=a2.y*u;  acc[10]+=a2.z*u; acc[11]+=a2.w*u;
    acc[12]+=a3.x*u; acc[13]+=a3.y*u; acc[14]+=a3.z*u; acc[15]+=a3.w*u;
  }
  const int e4 = t>>2, j = t&3;
  uint16_t* base = UK + (size_t)b*NS*ND + (size_t)e4*(NS*4) + j;
  #pragma unroll
  for (int i=0;i<16;i++)
    base[(size_t)(s0+i)*4] = f2bf(acc[i]);
}

// h0 = e_last, x0 = 0, q0 = h0 @ Wa^T + ba
__global__ void __launch_bounds__(256) k_init(const float* __restrict__ e_last,
    const float* __restrict__ WaT, const float* __restrict__ ba,
    float* __restrict__ h_ws, float* __restrict__ q_ws, float* __restrict__ x_ws){
  __shared__ float hl[ND];
  const int b = blockIdx.x, t = threadIdx.x;
  float hv = e_last[(size_t)b*ND + t];
  hl[t] = hv;
  h_ws[(size_t)b*ND + t] = hv;
  if (t < 4) x_ws[b*4 + t] = 0.f;
  __syncthreads();
  float acc = ba[t];
  for (int k=0;k<ND;k++) acc += hl[k]*WaT[k*ND + t];
  q_ws[(size_t)b*ND + t] = acc;
}

// ---------------- per-step kernels ----------------

// one block per batch b: scores -> softmax -> write w -> ctx
__global__ void __launch_bounds__(256) k_att(
    const uint16_t* __restrict__ UK, const uint16_t* __restrict__ EBF,
    const float* __restrict__ q_ws, const float* __restrict__ Va,
    const float* __restrict__ bv, float* __restrict__ ctx_ws,
    float* __restrict__ ca_out, int step)
{
  __shared__ float4 qv4[ND/2];      // {q[2i], Va[2i], q[2i+1], Va[2i+1]}
  __shared__ float  wl[NS];
  __shared__ float  red[8];
  __shared__ float  cpart[4][ND];
  const int t = threadIdx.x;
  const int b = blockIdx.x;
  const int lane = t & 63, wid = t >> 6;

  if (t < ND/2){
    float2 q2 = *(const float2*)(q_ws + (size_t)b*ND + 2*t);
    float2 v2 = *(const float2*)(Va + 2*t);
    qv4[t] = make_float4(q2.x, v2.x, q2.y, v2.y);
  }
  __syncthreads();

  // scores: thread t owns source position s=t; UK interleaved so 4 d's load as uint2
  const uint16_t* ukb = UK + (size_t)b*NS*ND;
  float acc = 0.f;
  #pragma unroll 4
  for (int e4=0; e4<ND/4; ++e4){
    uint2 u = *(const uint2*)(ukb + e4*(NS*4) + t*4);
    float4 a = qv4[e4*2+0];
    float4 c = qv4[e4*2+1];
    acc += tanh_f(bflo(u.x)+a.x)*a.y;
    acc += tanh_f(bfhi(u.x)+a.z)*a.w;
    acc += tanh_f(bflo(u.y)+c.x)*c.y;
    acc += tanh_f(bfhi(u.y)+c.z)*c.w;
  }
  float sc = acc + bv[0];

  // block softmax over 256 scores (one per thread)
  float m = sc;
  #pragma unroll
  for (int o=32;o;o>>=1) m = fmaxf(m, __shfl_xor(m,o));
  if (lane==0) red[wid] = m;
  __syncthreads();
  m = fmaxf(fmaxf(red[0],red[1]), fmaxf(red[2],red[3]));
  float p = exp2_fast((sc - m)*LOG2E);
  float ss = p;
  #pragma unroll
  for (int o=32;o;o>>=1) ss += __shfl_xor(ss,o);
  if (lane==0) red[4+wid] = ss;
  __syncthreads();
  ss = (red[4]+red[5])+(red[6]+red[7]);
  float w = p * rcp_fast(ss);
  wl[t] = w;
  ca_out[(size_t)b*(NT*NS) + (size_t)step*NS + t] = w;
  __syncthreads();

  // ctx[d] = sum_s w[s]*e[s,d]; wave wid covers s-chunk, lane covers d=lane*4..+3
  const uint16_t* eb = EBF + (size_t)b*NS*ND;
  float c0=0,c1=0,c2=0,c3=0;
  #pragma unroll 4
  for (int i=0;i<NS/4;i++){
    int s = wid*(NS/4) + i;
    float wf = wl[s];
    uint2 u = *(const uint2*)(eb + (size_t)s*ND + lane*4);
    c0 += wf*bflo(u.x); c1 += wf*bfhi(u.x);
    c2 += wf*bflo(u.y); c3 += wf*bfhi(u.y);
  }
  *(float4*)&cpart[wid][lane*4] = make_float4(c0,c1,c2,c3);
  __syncthreads();
  float ctxv = (cpart[0][t]+cpart[1][t]) + (cpart[2][t]+cpart[3][t]);
  ctx_ws[(size_t)b*ND + t] = ctxv;
}

// block handles 4 batch rows; thread t owns gate columns (t, t+256, t+512)
__global__ void __launch_bounds__(256) k_gru(
    const float* __restrict__ WihT, const float* __restrict__ WhhT,
    const float* __restrict__ WaT, const float* __restrict__ Wo,
    const float* __restrict__ b_ih, const float* __restrict__ b_hh,
    const float* __restrict__ ba, const float* __restrict__ bo,
    const float* __restrict__ ctx_ws, float* __restrict__ h_ws,
    float* __restrict__ q_ws, float* __restrict__ x_ws,
    float* __restrict__ dout, float* __restrict__ hT_out, int step)
{
  __shared__ float xc[KIH+1][4];   // [k][row] -> one b128 broadcast gives 4 rows
  __shared__ float hl[ND][4];
  __shared__ float hn[ND][4];
  const int t = threadIdx.x;
  const int b0 = blockIdx.x*4;
  #pragma unroll
  for (int r=0;r<4;r++){
    xc[t][r] = ctx_ws[(size_t)(b0+r)*ND + t];
    hl[t][r] = h_ws[(size_t)(b0+r)*ND + t];
  }
  if (t < NO){
    #pragma unroll
    for (int r=0;r<4;r++) xc[ND+t][r] = x_ws[(b0+r)*4 + t];
  }
  __syncthreads();

  float air[4],aiz[4],ain[4];
  {
    float br = b_ih[t], bz = b_ih[ND+t], bn = b_ih[2*ND+t];
    #pragma unroll
    for (int r=0;r<4;r++){ air[r]=br; aiz[r]=bz; ain[r]=bn; }
  }
  for (int k=0;k<KIH;k++){
    float4 xv = *(const float4*)&xc[k][0];
    float wr = WihT[(size_t)k*G3 + t];
    float wz = WihT[(size_t)k*G3 + ND + t];
    float wn = WihT[(size_t)k*G3 + 2*ND + t];
    air[0]+=xv.x*wr; air[1]+=xv.y*wr; air[2]+=xv.z*wr; air[3]+=xv.w*wr;
    aiz[0]+=xv.x*wz; aiz[1]+=xv.y*wz; aiz[2]+=xv.z*wz; aiz[3]+=xv.w*wz;
    ain[0]+=xv.x*wn; ain[1]+=xv.y*wn; ain[2]+=xv.z*wn; ain[3]+=xv.w*wn;
  }
  float ahr[4],ahz[4],ahn[4];
  {
    float br = b_hh[t], bz = b_hh[ND+t], bn = b_hh[2*ND+t];
    #pragma unroll
    for (int r=0;r<4;r++){ ahr[r]=br; ahz[r]=bz; ahn[r]=bn; }
  }
  for (int k=0;k<ND;k++){
    float4 hv = *(const float4*)&hl[k][0];
    float wr = WhhT[(size_t)k*G3 + t];
    float wz = WhhT[(size_t)k*G3 + ND + t];
    float wn = WhhT[(size_t)k*G3 + 2*ND + t];
    ahr[0]+=hv.x*wr; ahr[1]+=hv.y*wr; ahr[2]+=hv.z*wr; ahr[3]+=hv.w*wr;
    ahz[0]+=hv.x*wz; ahz[1]+=hv.y*wz; ahz[2]+=hv.z*wz; ahz[3]+=hv.w*wz;
    ahn[0]+=hv.x*wn; ahn[1]+=hv.y*wn; ahn[2]+=hv.z*wn; ahn[3]+=hv.w*wn;
  }
  float hnew[4];
  #pragma unroll
  for (int r=0;r<4;r++){
    float rg = sigm_f(air[r]+ahr[r]);
    float zg = sigm_f(aiz[r]+ahz[r]);
    float ng = tanh_f(ain[r] + rg*ahn[r]);
    float hp = hl[t][r];
    float hv = (1.f-zg)*ng + zg*hp;
    hnew[r] = hv;
    hn[t][r] = hv;
    h_ws[(size_t)(b0+r)*ND + t] = hv;
  }
  if (step == NT-1){
    #pragma unroll
    for (int r=0;r<4;r++) hT_out[(size_t)(b0+r)*ND + t] = hnew[r];
  }
  __syncthreads();

  // q_{t+1} = h_new @ Wa^T + ba
  float aq[4];
  { float bav = ba[t];
    #pragma unroll
    for (int r=0;r<4;r++) aq[r]=bav; }
  for (int k=0;k<ND;k++){
    float4 hv = *(const float4*)&hn[k][0];
    float wq = WaT[k*ND + t];
    aq[0]+=hv.x*wq; aq[1]+=hv.y*wq; aq[2]+=hv.z*wq; aq[3]+=hv.w*wq;
  }
  #pragma unroll
  for (int r=0;r<4;r++) q_ws[(size_t)(b0+r)*ND + t] = aq[r];

  // out = h_new @ Wo^T + bo ; wave wid handles row r=wid
  float p0=0,p1=0,p2=0;
  const int lane = t & 63, wid = t >> 6;
  #pragma unroll
  for (int it=0; it<4; ++it){
    int k = it*64 + lane;
    float hv = hn[k][wid];
    p0 += hv*Wo[k]; p1 += hv*Wo[ND+k]; p2 += hv*Wo[2*ND+k];
  }
  #pragma unroll
  for (int o=32;o;o>>=1){ p0+=__shfl_xor(p0,o); p1+=__shfl_xor(p1,o); p2+=__shfl_xor(p2,o); }
  if (lane==0){
    int bb = b0 + wid;
    float o0=p0+bo[0], o1=p1+bo[1], o2=p2+bo[2];
    dout[(size_t)bb*(NT*NO) + (size_t)step*NO + 0] = o0;
    dout[(size_t)bb*(NT*NO) + (size_t)step*NO + 1] = o1;
    dout[(size_t)bb*(NT*NO) + (size_t)step*NO + 2] = o2;
    x_ws[bb*4+0]=o0; x_ws[bb*4+1]=o1; x_ws[bb*4+2]=o2;
  }
}

// ---------------- host launch ----------------

extern "C" void kernel_launch(void* const* d_in, const int* in_sizes, int n_in,
                              void* d_out, int out_size, void* d_ws, size_t ws_size,
                              hipStream_t stream) {
  const float* e_all  = (const float*)d_in[0];
  const float* e_last = (const float*)d_in[1];
  const float* Wa     = (const float*)d_in[2];
  const float* ba     = (const float*)d_in[3];
  const float* Ua     = (const float*)d_in[4];
  const float* bu     = (const float*)d_in[5];
  const float* Va     = (const float*)d_in[6];
  const float* bv     = (const float*)d_in[7];
  const float* W_ih   = (const float*)d_in[8];
  const float* b_ih   = (const float*)d_in[9];
  const float* W_hh   = (const float*)d_in[10];
  const float* b_hh   = (const float*)d_in[11];
  const float* Wo     = (const float*)d_in[12];
  const float* bo     = (const float*)d_in[13];

  // workspace layout (needs ~132 MB)
  char* ws = (char*)d_ws;
  uint16_t* UK   = (uint16_t*)(ws + 0ull);           // bf16 [B][D/4][S][4]   67108864 B
  uint16_t* EBF  = (uint16_t*)(ws + 67108864ull);    // bf16 [B][S][D]        67108864 B
  float*    WihT = (float*)(ws + 134217728ull);      // f32 [259][768]          795648 B
  float*    WhhT = (float*)(ws + 135013376ull);      // f32 [256][768]          786432 B
  float*    WaT  = (float*)(ws + 135799808ull);      // f32 [256][256]          262144 B
  float*    UaT  = (float*)(ws + 136061952ull);      // f32 [256][256]          262144 B
  float*    Hws  = (float*)(ws + 136324096ull);      // f32 [B][D]
  float*    Qws  = (float*)(ws + 136848384ull);      // f32 [B][D]
  float*    Cws  = (float*)(ws + 137372672ull);      // f32 [B][D]
  float*    Xws  = (float*)(ws + 137896960ull);      // f32 [B][4]

  float* dout = (float*)d_out;                       // [B][T][3]
  float* hT   = dout + (size_t)NB*NT*NO;             // [B][D]
  float* ca   = hT   + (size_t)NB*ND;                // [B][T*S]

  // prep
  k_transpose<<<(G3*KIH+255)/256,256,0,stream>>>(W_ih, WihT, G3, KIH);
  k_transpose<<<(G3*ND +255)/256,256,0,stream>>>(W_hh, WhhT, G3, ND);
  k_transpose<<<(ND*ND +255)/256,256,0,stream>>>(Wa,  WaT,  ND, ND);
  k_transpose<<<(ND*ND +255)/256,256,0,stream>>>(Ua,  UaT,  ND, ND);
  k_cvt<<<((NB*NS*ND/4)+255)/256,256,0,stream>>>(e_all, EBF, NB*NS*ND/4);
  k_uk<<<NB*NS/16,256,0,stream>>>(e_all, UaT, bu, UK);
  k_init<<<NB,256,0,stream>>>(e_last, WaT, ba, Hws, Qws, Xws);

  // 256 decode steps
  for (int t=0; t<NT; ++t){
    k_att<<<NB,   256,0,stream>>>(UK, EBF, Qws, Va, bv, Cws, ca, t);
    k_gru<<<NB/4, 256,0,stream>>>(WihT,WhhT,WaT,Wo,b_ih,b_hh,ba,bo,Cws,Hws,Qws,Xws,dout,hT,t);
  }
}

// Round 2
// 18572.932 us; speedup vs baseline: 1.1424x; 1.1424x over previous
//
#include <hip/hip_runtime.h>
#include <hip/hip_bf16.h>
#include <stdint.h>

// Problem sizes (fixed)
#define NB 512     // batch
#define NS 256     // source length
#define ND 256     // hidden dim
#define NT 256     // decode steps
#define NO 3       // output dim

#define LOG2E 1.44269504088896340736f
#define C2 (2.0f*LOG2E)

#if __has_builtin(__builtin_amdgcn_exp2f)
__device__ __forceinline__ float exp2_fast(float x){ return __builtin_amdgcn_exp2f(x); }
#else
__device__ __forceinline__ float exp2_fast(float x){ return exp2f(x); }
#endif
#if __has_builtin(__builtin_amdgcn_rcpf)
__device__ __forceinline__ float rcp_fast(float x){ return __builtin_amdgcn_rcpf(x); }
#else
__device__ __forceinline__ float rcp_fast(float x){ return 1.0f/x; }
#endif

__device__ __forceinline__ float tanh_f(float x){
  float e = exp2_fast(x * C2);
  return 1.0f - 2.0f*rcp_fast(e + 1.0f);
}
// tanh with pre-scaled argument z = x * 2*log2e
__device__ __forceinline__ float tanh_pre(float z){
  return 1.0f - 2.0f*rcp_fast(exp2_fast(z) + 1.0f);
}
__device__ __forceinline__ float sigm_f(float x){
  return rcp_fast(1.0f + exp2_fast(-x*LOG2E));
}
__device__ __forceinline__ float bflo(uint32_t u){ return __uint_as_float(u<<16); }
__device__ __forceinline__ float bfhi(uint32_t u){ return __uint_as_float(u & 0xffff0000u); }
__device__ __forceinline__ uint16_t f2bf(float f){   // round-to-nearest-even bf16
  uint32_t u = __float_as_uint(f);
  return (uint16_t)((u + 0x7fffu + ((u>>16)&1u)) >> 16);
}

// ---------------- prep kernels ----------------

// dst[c*R + r] = src[r*C + c]
__global__ void k_transpose(const float* __restrict__ src, float* __restrict__ dst,
                            int R, int C){
  int idx = blockIdx.x*256 + threadIdx.x;
  if (idx < R*C){
    int r = idx / C, c = idx - r*C;
    dst[c*R + r] = src[idx];
  }
}

__global__ void k_cvt(const float* __restrict__ src, uint16_t* __restrict__ dst, int n4){
  int i = blockIdx.x*256 + threadIdx.x;
  if (i < n4){
    float4 v = ((const float4*)src)[i];
    ushort4 o;
    o.x=f2bf(v.x); o.y=f2bf(v.y); o.z=f2bf(v.z); o.w=f2bf(v.w);
    ((ushort4*)dst)[i] = o;
  }
}

// UK[b][e4][s][4] (bf16, d-interleaved-by-4, PRE-SCALED by 2*log2e)
__global__ void __launch_bounds__(256) k_uk(const float* __restrict__ e_all,
    const float* __restrict__ UaT, const float* __restrict__ bu,
    uint16_t* __restrict__ UK){
  __shared__ float At[ND][20];
  const int t = threadIdx.x;
  const int m0 = blockIdx.x * 16;
  const int b  = m0 >> 8;
  const int s0 = m0 & (NS-1);
  #pragma unroll
  for (int i=0;i<16;i++)
    At[t][i] = e_all[(size_t)(m0+i)*ND + t];
  __syncthreads();
  float acc[16];
  float bue = bu[t];
  #pragma unroll
  for (int i=0;i<16;i++) acc[i] = bue;
  for (int d=0; d<ND; ++d){
    float u = UaT[d*ND + t];
    const float4 a0 = *(const float4*)&At[d][0];
    const float4 a1 = *(const float4*)&At[d][4];
    const float4 a2 = *(const float4*)&At[d][8];
    const float4 a3 = *(const float4*)&At[d][12];
    acc[0]+=a0.x*u;  acc[1]+=a0.y*u;  acc[2]+=a0.z*u;  acc[3]+=a0.w*u;
    acc[4]+=a1.x*u;  acc[5]+=a1.y*u;  acc[6]+=a1.z*u;  acc[7]+=a1.w*u;
    acc[8]+=a2.x*u;  acc[9]+=a2.y*u;  acc[10]+=a2.z*u; acc[11]+=a2.w*u;
    acc[12]+=a3.x*u; acc[13]+=a3.y*u; acc[14]+=a3.z*u; acc[15]+=a3.w*u;
  }
  const int e4 = t>>2, j = t&3;
  uint16_t* base = UK + (size_t)b*NS*ND + (size_t)e4*(NS*4) + j;
  #pragma unroll
  for (int i=0;i<16;i++)
    base[(size_t)(s0+i)*4] = f2bf(acc[i] * C2);
}

// PK[k2][g][d] uint32 = {bf16 W(2k2, g*256+d), bf16 W(2k2+1, ...)}
// K-axis: rows 0..258 = W_ih cols (k), row 259 = 0 pad, rows 260..515 = W_hh
__global__ void k_pack_gates(const float* __restrict__ W_ih, const float* __restrict__ W_hh,
                             uint32_t* __restrict__ PK){
  int idx = blockIdx.x*256 + threadIdx.x;   // = (k2*3+g)*256 + d
  if (idx >= 258*768) return;
  int d  = idx & 255;
  int gk = idx >> 8;
  int k2 = gk / 3, g = gk - k2*3;
  int col = g*256 + d;
  float w0, w1;
  if (k2 < 130){
    int k0 = 2*k2, k1 = 2*k2+1;
    w0 = (k0 < 259) ? W_ih[(size_t)col*259 + k0] : 0.f;
    w1 = (k1 < 259) ? W_ih[(size_t)col*259 + k1] : 0.f;
  } else {
    int kk = 2*k2 - 260;
    w0 = W_hh[(size_t)col*256 + kk];
    w1 = W_hh[(size_t)col*256 + kk + 1];
  }
  PK[idx] = (uint32_t)f2bf(w0) | ((uint32_t)f2bf(w1) << 16);
}

// PQ[k2][d] = {bf16 Wa[d][2k2], bf16 Wa[d][2k2+1]}
__global__ void k_pack_q(const float* __restrict__ Wa, uint32_t* __restrict__ PQ){
  int idx = blockIdx.x*256 + threadIdx.x;   // k2*256 + d
  if (idx >= 128*256) return;
  int d = idx & 255, k2 = idx >> 8;
  float w0 = Wa[(size_t)d*256 + 2*k2], w1 = Wa[(size_t)d*256 + 2*k2 + 1];
  PQ[idx] = (uint32_t)f2bf(w0) | ((uint32_t)f2bf(w1) << 16);
}

// ---------------- persistent decode kernel ----------------
// One block per batch element; 256 threads (4 waves); runs all 256 steps.
// LDS xvec layout: [0..255] ctx, [256..258] x_in, [259] zero pad, [260..515] h
__global__ void __launch_bounds__(256) k_decode(
    const uint16_t* __restrict__ UK, const uint16_t* __restrict__ EBF,
    const uint32_t* __restrict__ PK, const uint32_t* __restrict__ PQ,
    const float* __restrict__ e_last,
    const float* __restrict__ Va, const float* __restrict__ bv,
    const float* __restrict__ b_ih, const float* __restrict__ b_hh,
    const float* __restrict__ ba, const float* __restrict__ bo,
    const float* __restrict__ Wo,
    float* __restrict__ dout, float* __restrict__ hT_out, float* __restrict__ ca)
{
  __shared__ float xvec[520];
  __shared__ float qL[256];
  __shared__ float VaL[256];
  __shared__ float wl[256];
  __shared__ float cpart[4][256];
  __shared__ float red[2][4];

  const int t = threadIdx.x;
  const int d = t;
  const int lane = t & 63;
  const int w = t >> 6;
  const int b = blockIdx.x;

  // ---- init ----
  xvec[260+d] = e_last[(size_t)b*ND + d];
  if (d < 4) xvec[256+d] = 0.f;           // x_in = 0 (and pad slot 259 = 0)
  VaL[d] = Va[d];
  const float bias_r  = b_ih[d]       + b_hh[d];
  const float bias_z  = b_ih[256+d]   + b_hh[256+d];
  const float bias_ni = b_ih[512+d];
  const float bias_nh = b_hh[512+d];
  const float ba_d = ba[d];
  const float bv0  = bv[0];
  float wo0[4], wo1[4], wo2[4];
  if (w == 0){
    #pragma unroll
    for (int i=0;i<4;i++){
      int k = i*64 + lane;
      wo0[i] = Wo[k]; wo1[i] = Wo[256+k]; wo2[i] = Wo[512+k];
    }
  }
  const float bo0 = bo[0], bo1 = bo[1], bo2 = bo[2];

  const uint16_t* ukb = UK  + (size_t)b*NS*ND;
  const uint16_t* eb  = EBF + (size_t)b*NS*ND;
  float* ca_b = ca + (size_t)b*(NT*NS);
  float* do_b = dout + (size_t)b*(NT*NO);

  __syncthreads();

  for (int step=0; step<NT; ++step){
    // ---- q = (h @ Wa^T + ba) * 2log2e ----
    float aq = ba_d;
    #pragma unroll 4
    for (int k2=0;k2<128;k2++){
      uint32_t u = PQ[k2*256 + d];
      float2 hh = *(const float2*)&xvec[260+2*k2];
      aq += bflo(u)*hh.x;
      aq += bfhi(u)*hh.y;
    }
    qL[d] = aq * C2;
    __syncthreads();

    // ---- scores: s = d, loop over e (pre-scaled tanh) ----
    float acc = 0.f;
    #pragma unroll 4
    for (int e4=0;e4<64;e4++){
      uint2 u = *(const uint2*)(ukb + e4*(NS*4) + d*4);
      float4 qq = *(const float4*)&qL[e4*4];
      float4 vv = *(const float4*)&VaL[e4*4];
      acc += tanh_pre(bflo(u.x)+qq.x)*vv.x;
      acc += tanh_pre(bfhi(u.x)+qq.y)*vv.y;
      acc += tanh_pre(bflo(u.y)+qq.z)*vv.z;
      acc += tanh_pre(bfhi(u.y)+qq.w)*vv.w;
    }
    float sc = acc + bv0;

    // ---- softmax over 256 scores ----
    float m = sc;
    #pragma unroll
    for (int o=32;o;o>>=1) m = fmaxf(m, __shfl_xor(m,o));
    if (lane==0) red[0][w] = m;
    __syncthreads();
    m = fmaxf(fmaxf(red[0][0],red[0][1]), fmaxf(red[0][2],red[0][3]));
    float p = exp2_fast((sc - m)*LOG2E);
    float ss = p;
    #pragma unroll
    for (int o=32;o;o>>=1) ss += __shfl_xor(ss,o);
    if (lane==0) red[1][w] = ss;
    __syncthreads();
    ss = (red[1][0]+red[1][1])+(red[1][2]+red[1][3]);
    float wgt = p * rcp_fast(ss);
    wl[d] = wgt;
    ca_b[(size_t)step*NS + d] = wgt;
    __syncthreads();

    // ---- ctx: wave w covers s-chunk, lane covers 4 d's ----
    float c0=0,c1=0,c2=0,c3=0;
    #pragma unroll 4
    for (int i=0;i<64;i++){
      int s = w*64 + i;
      float wf = wl[s];
      uint2 u = *(const uint2*)(eb + (size_t)s*ND + lane*4);
      c0 += wf*bflo(u.x); c1 += wf*bfhi(u.x);
      c2 += wf*bflo(u.y); c3 += wf*bfhi(u.y);
    }
    *(float4*)&cpart[w][lane*4] = make_float4(c0,c1,c2,c3);
    __syncthreads();
    xvec[d] = (cpart[0][d]+cpart[1][d])+(cpart[2][d]+cpart[3][d]);
    __syncthreads();

    // ---- GRU gates: thread d owns gate cols (d, 256+d, 512+d) ----
    float ar = bias_r, az = bias_z, ani = bias_ni, anh = bias_nh;
    const uint32_t* pk = PK + d;
    #pragma unroll 4
    for (int k2=0;k2<130;k2++){
      float2 xx = *(const float2*)&xvec[2*k2];
      uint32_t wr_ = pk[(k2*3+0)*256];
      uint32_t wz_ = pk[(k2*3+1)*256];
      uint32_t wn_ = pk[(k2*3+2)*256];
      ar  += bflo(wr_)*xx.x; ar  += bfhi(wr_)*xx.y;
      az  += bflo(wz_)*xx.x; az  += bfhi(wz_)*xx.y;
      ani += bflo(wn_)*xx.x; ani += bfhi(wn_)*xx.y;
    }
    #pragma unroll 4
    for (int k2=130;k2<258;k2++){
      float2 xx = *(const float2*)&xvec[2*k2];
      uint32_t wr_ = pk[(k2*3+0)*256];
      uint32_t wz_ = pk[(k2*3+1)*256];
      uint32_t wn_ = pk[(k2*3+2)*256];
      ar  += bflo(wr_)*xx.x; ar  += bfhi(wr_)*xx.y;
      az  += bflo(wz_)*xx.x; az  += bfhi(wz_)*xx.y;
      anh += bflo(wn_)*xx.x; anh += bfhi(wn_)*xx.y;
    }
    float rg = sigm_f(ar);
    float zg = sigm_f(az);
    float ng = tanh_f(ani + rg*anh);
    float hold = xvec[260+d];
    float hnew = (1.f-zg)*ng + zg*hold;
    __syncthreads();              // all reads of xvec done
    xvec[260+d] = hnew;
    __syncthreads();              // h_new visible

    // ---- out projection (wave 0 only) ----
    if (w == 0){
      float p0=0,p1=0,p2=0;
      #pragma unroll
      for (int i=0;i<4;i++){
        float hv = xvec[260 + i*64 + lane];
        p0 += hv*wo0[i]; p1 += hv*wo1[i]; p2 += hv*wo2[i];
      }
      #pragma unroll
      for (int o=32;o;o>>=1){
        p0+=__shfl_xor(p0,o); p1+=__shfl_xor(p1,o); p2+=__shfl_xor(p2,o);
      }
      if (lane==0){
        float o0=p0+bo0, o1=p1+bo1, o2=p2+bo2;
        size_t base = (size_t)step*NO;
        do_b[base+0]=o0; do_b[base+1]=o1; do_b[base+2]=o2;
        xvec[256]=o0; xvec[257]=o1; xvec[258]=o2;
      }
    }
    // next iteration's barriers order x_in writes before gate reads
  }

  __syncthreads();
  hT_out[(size_t)b*ND + d] = xvec[260+d];
}

// ---------------- host launch ----------------

extern "C" void kernel_launch(void* const* d_in, const int* in_sizes, int n_in,
                              void* d_out, int out_size, void* d_ws, size_t ws_size,
                              hipStream_t stream) {
  const float* e_all  = (const float*)d_in[0];
  const float* e_last = (const float*)d_in[1];
  const float* Wa     = (const float*)d_in[2];
  const float* ba     = (const float*)d_in[3];
  const float* Ua     = (const float*)d_in[4];
  const float* bu     = (const float*)d_in[5];
  const float* Va     = (const float*)d_in[6];
  const float* bv     = (const float*)d_in[7];
  const float* W_ih   = (const float*)d_in[8];
  const float* b_ih   = (const float*)d_in[9];
  const float* W_hh   = (const float*)d_in[10];
  const float* b_hh   = (const float*)d_in[11];
  const float* Wo     = (const float*)d_in[12];
  const float* bo     = (const float*)d_in[13];

  // workspace layout (~135.5 MB)
  char* ws = (char*)d_ws;
  uint16_t* UK   = (uint16_t*)(ws + 0ull);           // bf16 [B][D/4][S][4]  67108864 B
  uint16_t* EBF  = (uint16_t*)(ws + 67108864ull);    // bf16 [B][S][D]       67108864 B
  uint32_t* PK   = (uint32_t*)(ws + 134217728ull);   // u32  [258][3][256]     792576 B
  uint32_t* PQ   = (uint32_t*)(ws + 135010304ull);   // u32  [128][256]        131072 B
  float*    UaT  = (float*)(ws + 135141376ull);      // f32  [256][256]        262144 B

  float* dout = (float*)d_out;                       // [B][T][3]
  float* hT   = dout + (size_t)NB*NT*NO;             // [B][D]
  float* ca   = hT   + (size_t)NB*ND;                // [B][T*S]

  // prep
  k_transpose<<<(ND*ND+255)/256,256,0,stream>>>(Ua, UaT, ND, ND);
  k_cvt<<<((NB*NS*ND/4)+255)/256,256,0,stream>>>(e_all, EBF, NB*NS*ND/4);
  k_uk<<<NB*NS/16,256,0,stream>>>(e_all, UaT, bu, UK);
  k_pack_gates<<<(258*768+255)/256,256,0,stream>>>(W_ih, W_hh, PK);
  k_pack_q<<<(128*256+255)/256,256,0,stream>>>(Wa, PQ);

  // persistent decode: 1 block per batch element, all 256 steps inside
  k_decode<<<NB,256,0,stream>>>(UK, EBF, PK, PQ, e_last, Va, bv,
                                b_ih, b_hh, ba, bo, Wo, dout, hT, ca);
}